// Round 1
// baseline (219.150 us; speedup 1.0000x reference)
//
#include <hip/hip_runtime.h>
#include <hip/hip_bf16.h>
#include <cstdint>
#include <cstddef>

// Problem constants (fixed by the reference setup)
#define BB 4
#define TT 2048
#define DM 1024
#define DH 64

typedef __attribute__((ext_vector_type(8))) short short8;   // 8 bf16 (4 VGPRs)
typedef __attribute__((ext_vector_type(4))) float floatx4;  // MFMA C/D

__device__ __forceinline__ unsigned short f2bf(float f) {
    union { float f; unsigned int u; } v; v.f = f;
    unsigned int u = v.u;
    u += 0x7fffu + ((u >> 16) & 1u);   // RNE; inputs are finite
    return (unsigned short)(u >> 16);
}

// ---------------------------------------------------------------------------
// Kernel 0: convert W_Q (rows 0..63) and W_K (rows 64..127) to bf16 [128][1024]
// ---------------------------------------------------------------------------
__global__ __launch_bounds__(256) void wconv_kernel(const float* __restrict__ wq,
                                                    const float* __restrict__ wk,
                                                    unsigned short* __restrict__ wb) {
    int i = blockIdx.x * 256 + threadIdx.x;          // 0..32767, 4 elems each
    const float* src = (i < 16384) ? (wq + (size_t)i * 4)
                                   : (wk + (size_t)(i - 16384) * 4);
    float4 v = *reinterpret_cast<const float4*>(src);
    ushort4 o;
    o.x = f2bf(v.x); o.y = f2bf(v.y); o.z = f2bf(v.z); o.w = f2bf(v.w);
    *reinterpret_cast<ushort4*>(wb + (size_t)i * 4) = o;
}

// ---------------------------------------------------------------------------
// Kernel 1: projection GEMM. Q = x*W_Q^T (pre-scaled by 1/32), K = x*W_K^T.
// One wave per 16-row m-tile; 8 n-tiles (64 Q cols + 64 K cols).
// A-frag: x fp32 -> bf16 inline. B-frag: bf16 W direct from global (L2-hot).
// ---------------------------------------------------------------------------
__global__ __launch_bounds__(64) void proj_kernel(const float* __restrict__ x,
                                                  const unsigned short* __restrict__ wb,
                                                  unsigned short* __restrict__ qo,
                                                  unsigned short* __restrict__ ko) {
    const int lane = threadIdx.x;
    const int col  = lane & 15;
    const int quad = lane >> 4;
    const int m0   = blockIdx.x * 16;

    floatx4 acc[8];
#pragma unroll
    for (int i = 0; i < 8; ++i) acc[i] = (floatx4){0.f, 0.f, 0.f, 0.f};

    const float* xp = x + (size_t)(m0 + col) * DM + quad * 8;

#pragma unroll 2
    for (int k0 = 0; k0 < DM; k0 += 32) {
        float4 xa = *reinterpret_cast<const float4*>(xp + k0);
        float4 xb = *reinterpret_cast<const float4*>(xp + k0 + 4);
        short8 a;
        a[0] = (short)f2bf(xa.x); a[1] = (short)f2bf(xa.y);
        a[2] = (short)f2bf(xa.z); a[3] = (short)f2bf(xa.w);
        a[4] = (short)f2bf(xb.x); a[5] = (short)f2bf(xb.y);
        a[6] = (short)f2bf(xb.z); a[7] = (short)f2bf(xb.w);
#pragma unroll
        for (int nt = 0; nt < 8; ++nt) {
            short8 b = *reinterpret_cast<const short8*>(
                wb + (size_t)(nt * 16 + col) * DM + k0 + quad * 8);
            acc[nt] = __builtin_amdgcn_mfma_f32_16x16x32_bf16(a, b, acc[nt], 0, 0, 0);
        }
    }

    // Epilogue: C/D layout col=lane&15, row=quad*4+reg. Q gets exact 1/32 scale.
#pragma unroll
    for (int nt = 0; nt < 8; ++nt) {
        const int n = nt * 16 + col;
#pragma unroll
        for (int r = 0; r < 4; ++r) {
            const size_t row = (size_t)(m0 + quad * 4 + r);
            float v = acc[nt][r];
            if (nt < 4) qo[row * DH + n]        = f2bf(v * 0.03125f);
            else        ko[row * DH + (n - 64)] = f2bf(v);
        }
    }
}

// ---------------------------------------------------------------------------
// Kernel 2: causal flash attention, O = softmax(Q K^T, causal) K   (V == K).
// Block: 128 threads (2 waves), 32 q-rows; wave w owns rows q0+16w..+15.
// Key loop: 32 keys/iter. K staged in LDS both [s][d] (QK^T B-frags) and
// [d][s] (PV B-frags). P relayout C->A through per-wave LDS scratch.
// ---------------------------------------------------------------------------
__global__ __launch_bounds__(128) void flash_kernel(const unsigned short* __restrict__ qb,
                                                    const unsigned short* __restrict__ kb,
                                                    float* __restrict__ out) {
    __shared__ __align__(16) unsigned short Ks[32][64];     // [s][d]
    __shared__ __align__(16) unsigned short Kt[64][32];     // [d][s]
    __shared__ __align__(16) unsigned short Pl[2][16][32];  // per-wave P scratch

    const int tid  = threadIdx.x;
    const int wave = tid >> 6;
    const int lane = tid & 63;
    const int col  = lane & 15;
    const int quad = lane >> 4;

    const int b    = blockIdx.x >> 6;    // batch
    const int qt   = blockIdx.x & 63;    // q-tile within batch
    const int q0   = qt * 32;
    const int qrow = q0 + wave * 16;     // wave's first q row

    const unsigned short* qbase = qb + ((size_t)b * TT + qrow) * DH;
    const unsigned short* kbase = kb + (size_t)b * TT * DH;

    // Q A-frags (Q already scaled by 1/32): lane -> row col, k = quad*8+j (+32)
    short8 qf0 = *reinterpret_cast<const short8*>(qbase + (size_t)col * DH + quad * 8);
    short8 qf1 = *reinterpret_cast<const short8*>(qbase + (size_t)col * DH + 32 + quad * 8);

    floatx4 o[4];
#pragma unroll
    for (int t = 0; t < 4; ++t) o[t] = (floatx4){0.f, 0.f, 0.f, 0.f};
    float mrow[4], lrow[4];
    int   myq[4];
#pragma unroll
    for (int r = 0; r < 4; ++r) {
        mrow[r] = -INFINITY; lrow[r] = 0.f;
        myq[r] = qrow + quad * 4 + r;
    }

    const float LOG2E = 1.44269504f;
    const int s_end = q0 + 32;   // causal: keys needed are < q0+32

    for (int s0 = 0; s0 < s_end; s0 += 32) {
        // ---- stage K tile (32 keys x 64 d), both layouts ----
        {
            const int s  = tid >> 2;            // 0..31
            const int d0 = (tid & 3) * 16;      // 0,16,32,48
            const unsigned short* src = kbase + (size_t)(s0 + s) * DH + d0;
            short8 v0 = *reinterpret_cast<const short8*>(src);
            short8 v1 = *reinterpret_cast<const short8*>(src + 8);
            *reinterpret_cast<short8*>(&Ks[s][d0])     = v0;
            *reinterpret_cast<short8*>(&Ks[s][d0 + 8]) = v1;
#pragma unroll
            for (int j = 0; j < 8; ++j) {
                Kt[d0 + j][s]     = (unsigned short)v0[j];
                Kt[d0 + 8 + j][s] = (unsigned short)v1[j];
            }
        }
        __syncthreads();

        // ---- S = Q K^T (two 16-key subtiles), then scale to log2 + mask ----
        float sv[2][4];
        float mtile[4];
#pragma unroll
        for (int r = 0; r < 4; ++r) mtile[r] = -INFINITY;
#pragma unroll
        for (int st = 0; st < 2; ++st) {
            short8 kf0 = *reinterpret_cast<const short8*>(&Ks[st * 16 + col][quad * 8]);
            short8 kf1 = *reinterpret_cast<const short8*>(&Ks[st * 16 + col][32 + quad * 8]);
            floatx4 z = (floatx4){0.f, 0.f, 0.f, 0.f};
            z = __builtin_amdgcn_mfma_f32_16x16x32_bf16(qf0, kf0, z, 0, 0, 0);
            z = __builtin_amdgcn_mfma_f32_16x16x32_bf16(qf1, kf1, z, 0, 0, 0);
            const int skey = s0 + st * 16 + col;
#pragma unroll
            for (int r = 0; r < 4; ++r) {
                float v = z[r] * LOG2E;                    // scores in log2 domain
                v = (skey <= myq[r]) ? v : -INFINITY;      // causal mask
                sv[st][r] = v;
                mtile[r] = fmaxf(mtile[r], v);
            }
        }
        // row-max across the 16 lanes holding this row's columns
#pragma unroll
        for (int m = 1; m < 16; m <<= 1)
#pragma unroll
            for (int r = 0; r < 4; ++r)
                mtile[r] = fmaxf(mtile[r], __shfl_xor(mtile[r], m, 64));

        // ---- online softmax update ----
        float alpha[4], rsum[4];
#pragma unroll
        for (int r = 0; r < 4; ++r) {
            float mnew = fmaxf(mrow[r], mtile[r]);
            alpha[r] = exp2f(mrow[r] - mnew);              // exp2(-inf)=0 first iter
            mrow[r] = mnew;
            float p0 = exp2f(sv[0][r] - mnew);
            float p1 = exp2f(sv[1][r] - mnew);
            sv[0][r] = p0; sv[1][r] = p1;
            rsum[r] = p0 + p1;
        }
#pragma unroll
        for (int m = 1; m < 16; m <<= 1)
#pragma unroll
            for (int r = 0; r < 4; ++r)
                rsum[r] += __shfl_xor(rsum[r], m, 64);
#pragma unroll
        for (int r = 0; r < 4; ++r) lrow[r] = lrow[r] * alpha[r] + rsum[r];
#pragma unroll
        for (int t = 0; t < 4; ++t)
#pragma unroll
            for (int r = 0; r < 4; ++r)
                o[t][r] *= alpha[r];

        // ---- P: C-layout regs -> A-layout via per-wave LDS scratch ----
#pragma unroll
        for (int st = 0; st < 2; ++st)
#pragma unroll
            for (int r = 0; r < 4; ++r)
                Pl[wave][quad * 4 + r][st * 16 + col] = f2bf(sv[st][r]);
        __syncthreads();   // (conservative; P is wave-private)

        short8 pf = *reinterpret_cast<const short8*>(&Pl[wave][col][quad * 8]);

        // ---- O += P V  (V == K), B-frags from transposed Kt ----
#pragma unroll
        for (int t = 0; t < 4; ++t) {
            short8 vf = *reinterpret_cast<const short8*>(&Kt[t * 16 + col][quad * 8]);
            o[t] = __builtin_amdgcn_mfma_f32_16x16x32_bf16(pf, vf, o[t], 0, 0, 0);
        }
        __syncthreads();   // guard Ks/Kt overwrite next iteration
    }

    // ---- epilogue: O / l, fp32 out ----
    float inv[4];
#pragma unroll
    for (int r = 0; r < 4; ++r) inv[r] = 1.0f / lrow[r];
    float* obase = out + ((size_t)b * TT + qrow) * DH;
#pragma unroll
    for (int t = 0; t < 4; ++t)
#pragma unroll
        for (int r = 0; r < 4; ++r)
            obase[(size_t)(quad * 4 + r) * DH + t * 16 + col] = o[t][r] * inv[r];
}

// ---------------------------------------------------------------------------
extern "C" void kernel_launch(void* const* d_in, const int* in_sizes, int n_in,
                              void* d_out, int out_size, void* d_ws, size_t ws_size,
                              hipStream_t stream) {
    const float* x  = (const float*)d_in[0];
    const float* wq = (const float*)d_in[1];
    const float* wk = (const float*)d_in[2];
    // d_in[3] (W_V) is unused — faithful to the reference's source bug.

    unsigned short* qo = (unsigned short*)d_ws;          // [8192][64] bf16 (pre-scaled 1/32)
    unsigned short* ko = qo + (size_t)BB * TT * DH;      // [8192][64] bf16
    unsigned short* wb = ko + (size_t)BB * TT * DH;      // [128][1024] bf16
    float* out = (float*)d_out;

    hipLaunchKernelGGL(wconv_kernel, dim3(128), dim3(256), 0, stream, wq, wk, wb);
    hipLaunchKernelGGL(proj_kernel,  dim3((BB * TT) / 16), dim3(64), 0, stream, x, wb, qo, ko);
    hipLaunchKernelGGL(flash_kernel, dim3(BB * (TT / 32)), dim3(128), 0, stream, qo, ko, out);
}

// Round 2
// 137.712 us; speedup vs baseline: 1.5914x; 1.5914x over previous
//
#include <hip/hip_runtime.h>
#include <hip/hip_bf16.h>
#include <cstdint>
#include <cstddef>

// Problem constants (fixed by the reference setup)
#define BB 4
#define TT 2048
#define DM 1024
#define DH 64

typedef __attribute__((ext_vector_type(8))) short short8;   // 8 bf16 (4 VGPRs)
typedef __attribute__((ext_vector_type(4))) float floatx4;  // MFMA C/D

__device__ __forceinline__ unsigned short f2bf(float f) {
    union { float f; unsigned int u; } v; v.f = f;
    unsigned int u = v.u;
    u += 0x7fffu + ((u >> 16) & 1u);   // RNE; inputs are finite
    return (unsigned short)(u >> 16);
}

// ---------------------------------------------------------------------------
// Kernel 0: convert W_Q (rows 0..63) and W_K (rows 64..127) to bf16 [128][1024]
// ---------------------------------------------------------------------------
__global__ __launch_bounds__(256) void wconv_kernel(const float* __restrict__ wq,
                                                    const float* __restrict__ wk,
                                                    unsigned short* __restrict__ wb) {
    int i = blockIdx.x * 256 + threadIdx.x;          // 0..32767, 4 elems each
    const float* src = (i < 16384) ? (wq + (size_t)i * 4)
                                   : (wk + (size_t)(i - 16384) * 4);
    float4 v = *reinterpret_cast<const float4*>(src);
    ushort4 o;
    o.x = f2bf(v.x); o.y = f2bf(v.y); o.z = f2bf(v.z); o.w = f2bf(v.w);
    *reinterpret_cast<ushort4*>(wb + (size_t)i * 4) = o;
}

// ---------------------------------------------------------------------------
// Kernel 1: projection GEMM. 512 blocks x 2 waves. Block owns a 16-row m-tile;
// wave 0 computes the 64 Q cols (pre-scaled 1/32), wave 1 the 64 K cols.
// Both waves read the same x rows (L1-shared). K epilogue also writes the
// global transpose kt[b][d][s] for the flash PV B-frags.
// ---------------------------------------------------------------------------
__global__ __launch_bounds__(128) void proj_kernel(const float* __restrict__ x,
                                                   const unsigned short* __restrict__ wb,
                                                   unsigned short* __restrict__ qo,
                                                   unsigned short* __restrict__ ko,
                                                   unsigned short* __restrict__ kt) {
    const int tid  = threadIdx.x;
    const int wave = tid >> 6;          // 0 = Q half, 1 = K half
    const int lane = tid & 63;
    const int col  = lane & 15;
    const int quad = lane >> 4;
    const int m0   = blockIdx.x * 16;

    floatx4 acc[4];
#pragma unroll
    for (int i = 0; i < 4; ++i) acc[i] = (floatx4){0.f, 0.f, 0.f, 0.f};

    const float* xp = x + (size_t)(m0 + col) * DM + quad * 8;
    const unsigned short* wp = wb + (size_t)(wave * 64) * DM;

#pragma unroll 2
    for (int k0 = 0; k0 < DM; k0 += 32) {
        float4 xa = *reinterpret_cast<const float4*>(xp + k0);
        float4 xb = *reinterpret_cast<const float4*>(xp + k0 + 4);
        short8 a;
        a[0] = (short)f2bf(xa.x); a[1] = (short)f2bf(xa.y);
        a[2] = (short)f2bf(xa.z); a[3] = (short)f2bf(xa.w);
        a[4] = (short)f2bf(xb.x); a[5] = (short)f2bf(xb.y);
        a[6] = (short)f2bf(xb.z); a[7] = (short)f2bf(xb.w);
#pragma unroll
        for (int nt = 0; nt < 4; ++nt) {
            short8 b = *reinterpret_cast<const short8*>(
                wp + (size_t)(nt * 16 + col) * DM + k0 + quad * 8);
            acc[nt] = __builtin_amdgcn_mfma_f32_16x16x32_bf16(a, b, acc[nt], 0, 0, 0);
        }
    }

    // Epilogue: C/D layout col=lane&15, row=quad*4+reg.
#pragma unroll
    for (int nt = 0; nt < 4; ++nt) {
        const int n = nt * 16 + col;
#pragma unroll
        for (int r = 0; r < 4; ++r) {
            const size_t row = (size_t)(m0 + quad * 4 + r);
            float v = acc[nt][r];
            if (wave == 0) {
                qo[row * DH + n] = f2bf(v * 0.03125f);   // exact 1/sqrt(1024)
            } else {
                unsigned short h = f2bf(v);
                ko[row * DH + n] = h;
                const int b = (int)(row >> 11);
                const int s = (int)(row & 2047);
                kt[((size_t)(b * 64 + n)) * TT + s] = h; // transposed copy (L2-merged)
            }
        }
    }
}

// ---------------------------------------------------------------------------
// Kernel 2: flash phase 1 (split-K). Block = (b, qt, chunk); 2 waves, 32 q-rows,
// keys [256*chunk, min(256*chunk+256, q0+32)). No K staging: QK^T B-frags load
// from ko [s][d], PV B-frags from kt [d][s]. P relayout via wave-private LDS
// (no __syncthreads anywhere). Writes unnormalized O + (m,l) per chunk.
// ---------------------------------------------------------------------------
__global__ __launch_bounds__(128) void flash1_kernel(const unsigned short* __restrict__ qb,
                                                     const unsigned short* __restrict__ kb,
                                                     const unsigned short* __restrict__ ktb,
                                                     float* __restrict__ Op,
                                                     float* __restrict__ ml) {
    const int c  = blockIdx.x & 7;          // key chunk (256 keys)
    const int qt = (blockIdx.x >> 3) & 63;  // q-tile (32 rows)
    const int b  = blockIdx.x >> 9;         // batch
    if (8 * c > qt) return;                 // chunk entirely beyond causal range

    __shared__ __align__(16) unsigned short Pl[2][16][32];  // per-wave P scratch

    const int tid  = threadIdx.x;
    const int wave = tid >> 6;
    const int lane = tid & 63;
    const int col  = lane & 15;
    const int quad = lane >> 4;

    const int q0    = qt * 32;
    const int qrow  = q0 + wave * 16;
    const int s_beg = c * 256;
    const int s_end = min(s_beg + 256, q0 + 32);

    const unsigned short* qp  = qb  + ((size_t)b * TT + qrow) * DH;
    const unsigned short* kp  = kb  + (size_t)b * TT * DH;
    const unsigned short* ktp = ktb + (size_t)b * 64 * TT;

    // Q A-frags (Q pre-scaled by 1/32)
    short8 qf0 = *reinterpret_cast<const short8*>(qp + (size_t)col * DH + quad * 8);
    short8 qf1 = *reinterpret_cast<const short8*>(qp + (size_t)col * DH + 32 + quad * 8);

    floatx4 o[4];
#pragma unroll
    for (int t = 0; t < 4; ++t) o[t] = (floatx4){0.f, 0.f, 0.f, 0.f};
    float mrow[4], lrow[4];
    int   myq[4];
#pragma unroll
    for (int r = 0; r < 4; ++r) {
        mrow[r] = -INFINITY; lrow[r] = 0.f;
        myq[r] = qrow + quad * 4 + r;
    }
    const float LOG2E = 1.44269504f;

    for (int s0 = s_beg; s0 < s_end; s0 += 32) {
        // ---- S = Q K^T (two 16-key subtiles), log2 domain + causal mask ----
        float sv[2][4];
        float mtile[4];
#pragma unroll
        for (int r = 0; r < 4; ++r) mtile[r] = -INFINITY;
#pragma unroll
        for (int st = 0; st < 2; ++st) {
            const unsigned short* kr = kp + (size_t)(s0 + st * 16 + col) * DH + quad * 8;
            short8 kf0 = *reinterpret_cast<const short8*>(kr);
            short8 kf1 = *reinterpret_cast<const short8*>(kr + 32);
            floatx4 z = (floatx4){0.f, 0.f, 0.f, 0.f};
            z = __builtin_amdgcn_mfma_f32_16x16x32_bf16(qf0, kf0, z, 0, 0, 0);
            z = __builtin_amdgcn_mfma_f32_16x16x32_bf16(qf1, kf1, z, 0, 0, 0);
            const int skey = s0 + st * 16 + col;
#pragma unroll
            for (int r = 0; r < 4; ++r) {
                float v = z[r] * LOG2E;
                v = (skey <= myq[r]) ? v : -INFINITY;
                sv[st][r] = v;
                mtile[r] = fmaxf(mtile[r], v);
            }
        }
#pragma unroll
        for (int m = 1; m < 16; m <<= 1)
#pragma unroll
            for (int r = 0; r < 4; ++r)
                mtile[r] = fmaxf(mtile[r], __shfl_xor(mtile[r], m, 64));

        // ---- online softmax update ----
        float alpha[4], rsum[4];
#pragma unroll
        for (int r = 0; r < 4; ++r) {
            float mnew = fmaxf(mrow[r], mtile[r]);
            alpha[r] = exp2f(mrow[r] - mnew);
            mrow[r] = mnew;
            float p0 = exp2f(sv[0][r] - mnew);
            float p1 = exp2f(sv[1][r] - mnew);
            sv[0][r] = p0; sv[1][r] = p1;
            rsum[r] = p0 + p1;
        }
#pragma unroll
        for (int m = 1; m < 16; m <<= 1)
#pragma unroll
            for (int r = 0; r < 4; ++r)
                rsum[r] += __shfl_xor(rsum[r], m, 64);
#pragma unroll
        for (int r = 0; r < 4; ++r) lrow[r] = lrow[r] * alpha[r] + rsum[r];
#pragma unroll
        for (int t = 0; t < 4; ++t)
#pragma unroll
            for (int r = 0; r < 4; ++r)
                o[t][r] *= alpha[r];

        // ---- P: C-layout regs -> A-layout via wave-private LDS (no barrier) ----
#pragma unroll
        for (int st = 0; st < 2; ++st)
#pragma unroll
            for (int r = 0; r < 4; ++r)
                Pl[wave][quad * 4 + r][st * 16 + col] = f2bf(sv[st][r]);
        short8 pf = *reinterpret_cast<const short8*>(&Pl[wave][col][quad * 8]);

        // ---- O += P V  (V == K), B-frags from global kt [d][s] ----
#pragma unroll
        for (int t = 0; t < 4; ++t) {
            short8 vf = *reinterpret_cast<const short8*>(
                ktp + (size_t)(t * 16 + col) * TT + s0 + quad * 8);
            o[t] = __builtin_amdgcn_mfma_f32_16x16x32_bf16(pf, vf, o[t], 0, 0, 0);
        }
    }

    // ---- store partial (unnormalized O, m, l) ----
    const int slot = (b * 64 + qt) * 8 + c;
    float* op = Op + (size_t)slot * 2048;           // [32][64]
#pragma unroll
    for (int t = 0; t < 4; ++t)
#pragma unroll
        for (int r = 0; r < 4; ++r)
            op[(size_t)(wave * 16 + quad * 4 + r) * DH + t * 16 + col] = o[t][r];
    if (col == 0) {
        float* mlp = ml + (size_t)slot * 64;        // [m[32], l[32]]
#pragma unroll
        for (int r = 0; r < 4; ++r) {
            mlp[wave * 16 + quad * 4 + r]      = mrow[r];
            mlp[32 + wave * 16 + quad * 4 + r] = lrow[r];
        }
    }
}

// ---------------------------------------------------------------------------
// Kernel 3: merge split-K partials. Block per (b, qt); thread owns 8 cols of
// one row. O = (sum_c w_c * O_c) / (sum_c w_c * l_c), w_c = exp2(m_c - M).
// ---------------------------------------------------------------------------
__global__ __launch_bounds__(256) void merge_kernel(const float* __restrict__ Op,
                                                    const float* __restrict__ ml,
                                                    float* __restrict__ out) {
    const int qt  = blockIdx.x & 63;
    const int b   = blockIdx.x >> 6;
    const int nch = (qt >> 3) + 1;
    const int t   = threadIdx.x;
    const int row = t >> 3;           // 0..31
    const int c8  = (t & 7) * 8;      // col group of 8
    const size_t base = (size_t)blockIdx.x * 8;

    float M = -INFINITY;
    for (int c = 0; c < nch; ++c)
        M = fmaxf(M, ml[(base + c) * 64 + row]);

    float L = 0.f;
    float a[8];
#pragma unroll
    for (int i = 0; i < 8; ++i) a[i] = 0.f;
    for (int c = 0; c < nch; ++c) {
        const float m_c = ml[(base + c) * 64 + row];
        const float l_c = ml[(base + c) * 64 + 32 + row];
        const float w = exp2f(m_c - M);
        L += l_c * w;
        const float* op = Op + (base + c) * 2048 + (size_t)row * 64 + c8;
        float4 v0 = *reinterpret_cast<const float4*>(op);
        float4 v1 = *reinterpret_cast<const float4*>(op + 4);
        a[0] += w * v0.x; a[1] += w * v0.y; a[2] += w * v0.z; a[3] += w * v0.w;
        a[4] += w * v1.x; a[5] += w * v1.y; a[6] += w * v1.z; a[7] += w * v1.w;
    }
    const float inv = 1.0f / L;
    float* o = out + ((size_t)b * TT + qt * 32 + row) * DH + c8;
    float4 r0 = {a[0] * inv, a[1] * inv, a[2] * inv, a[3] * inv};
    float4 r1 = {a[4] * inv, a[5] * inv, a[6] * inv, a[7] * inv};
    *reinterpret_cast<float4*>(o)     = r0;
    *reinterpret_cast<float4*>(o + 4) = r1;
}

// ---------------------------------------------------------------------------
extern "C" void kernel_launch(void* const* d_in, const int* in_sizes, int n_in,
                              void* d_out, int out_size, void* d_ws, size_t ws_size,
                              hipStream_t stream) {
    const float* x  = (const float*)d_in[0];
    const float* wq = (const float*)d_in[1];
    const float* wk = (const float*)d_in[2];
    // d_in[3] (W_V) is unused — faithful to the reference's source bug.

    unsigned short* qo = (unsigned short*)d_ws;          // [8192][64]  bf16 (pre-scaled)
    unsigned short* ko = qo + (size_t)BB * TT * DH;      // [8192][64]  bf16
    unsigned short* wb = ko + (size_t)BB * TT * DH;      // [128][1024] bf16
    unsigned short* kt = wb + (size_t)128 * DM;          // [4][64][2048] bf16 (K^T)
    float* Op = (float*)(kt + (size_t)BB * DH * TT);     // [2048][32][64] fp32 partials
    float* ml = Op + (size_t)2048 * 2048;                // [2048][64] fp32 (m,l)
    float* out = (float*)d_out;

    hipLaunchKernelGGL(wconv_kernel,  dim3(128),            dim3(256), 0, stream, wq, wk, wb);
    hipLaunchKernelGGL(proj_kernel,   dim3((BB * TT) / 16), dim3(128), 0, stream, x, wb, qo, ko, kt);
    hipLaunchKernelGGL(flash1_kernel, dim3(BB * 64 * 8),    dim3(128), 0, stream, qo, ko, kt, Op, ml);
    hipLaunchKernelGGL(merge_kernel,  dim3(BB * 64),        dim3(256), 0, stream, Op, ml, out);
}